// Round 3
// baseline (126.902 us; speedup 1.0000x reference)
//
#include <hip/hip_runtime.h>

#define BS 16
#define NQ 200
#define NPTS 25
#define VOC 96
#define VOCP1 97
#define NGT 32
#define LSEQ 25
#define NCOL (BS*NGT)      // 512
#define NBQ (BS*NQ)        // 3200
#define KL_EPS 1e-6f
#define FOCAL_EPS 1e-8f

#define NB_CDIST 400                      // 50 row-tiles x 8 col-tiles
#define NB_SOFT VOC                       // 96 blocks: soft rows
#define NB_LOGP (NBQ/4)                   // 800 blocks: 4 waves, 1 wave = 1 bq
#define NB_K1 (NB_CDIST + NB_SOFT + NB_LOGP)  // 1296

// ==========================================================================
// K1: three independent block families, one launch, 13.3 KB LDS everywhere
// -> 8 blocks/CU (thread-limited) for all families.
//   [0, 400)    : 64x64 L1-cdist tiles. Only tgt tile staged in LDS
//                 ([64][50]: bank = 18*tx mod 32, all-distinct, conflict-free
//                 float2 reads); pred rows stream from global via L1
//                 broadcast (4 addrs/wave). cost_class recomputed locally.
//   [400, 496)  : soft[96,96] rows (0.85*I + 0.15*softmax(cos-sim))
//   [496, 1296) : logP — one wave per (b,q), 4 independent waves/block.
//                 No LDS, no barrier. Lane holds v=lane and v=64+lane;
//                 5-point load batching; renorm denom via blank identity
//                 sum_{v<96} avg = (25 - sum_p p_blank)/25.
// ==========================================================================
__global__ __launch_bounds__(256) void K1(
        const float* __restrict__ pred_logits,       // [NBQ, 25]
        const float* __restrict__ pred_ctrl,         // [NBQ, 50]
        const float* __restrict__ pred_text_logits,  // [NBQ, 25, 97]
        const float* __restrict__ tgt_ctrl,          // [512, 50]
        const float* __restrict__ centroids,         // [96, 256]
        float* __restrict__ logP,                    // [NBQ, 96]
        float* __restrict__ soft,                    // [96, 96]
        float* __restrict__ out)                     // [NBQ, 512]
{
    __shared__ __align__(16) float smem[64 * 50 + 64];   // 13.3 KB
    const int tid = threadIdx.x;
    const int bid = blockIdx.x;

    if (bid < NB_CDIST) {
        // ---------------- cdist + cost_class family ----------------
        const int r0  = (bid >> 3) * 64;
        const int c0  = (bid & 7) * 64;
        float (*s_t)[50] = (float (*)[50])smem;              // 64*50
        float* s_cc = smem + 3200;                           // 64

        const float* tg = tgt_ctrl + (size_t)c0 * 50;
        for (int i = tid; i < 64 * 50; i += 256)
            ((float*)s_t)[i] = tg[i];
        // cost_class for this tile's 64 rows: 4 threads/row
        {
            const int row4 = tid >> 2, q4 = tid & 3;
            float cc = 0.f;
            for (int p = q4; p < NPTS; p += 4) {
                float x  = pred_logits[(size_t)(r0 + row4) * NPTS + p];
                float pr = 1.f / (1.f + __expf(-x));
                float pos = 0.25f * (1.f - pr) * (1.f - pr) * (-__logf(pr + FOCAL_EPS));
                float neg = 0.75f * pr * pr * (-__logf(1.f - pr + FOCAL_EPS));
                cc += pos - neg;
            }
            cc += __shfl_xor(cc, 1, 4);
            cc += __shfl_xor(cc, 2, 4);
            if (q4 == 0) s_cc[row4] = cc * (1.0f / NPTS);
        }
        __syncthreads();

        const int tx = tid & 15;       // col group (cols tx+16j)
        const int ty = tid >> 4;       // row group (rows ty*4+i)
        const float* prow[4];
        #pragma unroll
        for (int i = 0; i < 4; i++)
            prow[i] = pred_ctrl + (size_t)(r0 + ty * 4 + i) * 50;

        float acc[4][4];
        #pragma unroll
        for (int i = 0; i < 4; i++)
            #pragma unroll
            for (int j = 0; j < 4; j++) acc[i][j] = 0.f;

        #pragma unroll
        for (int k = 0; k < 50; k += 2) {
            float2 p[4], t[4];
            #pragma unroll
            for (int i = 0; i < 4; i++) p[i] = *(const float2*)(prow[i] + k);
            #pragma unroll
            for (int j = 0; j < 4; j++) t[j] = *(const float2*)&s_t[tx + 16 * j][k];
            #pragma unroll
            for (int i = 0; i < 4; i++)
                #pragma unroll
                for (int j = 0; j < 4; j++)
                    acc[i][j] += fabsf(p[i].x - t[j].x) + fabsf(p[i].y - t[j].y);
        }

        #pragma unroll
        for (int i = 0; i < 4; i++) {
            const int row = ty * 4 + i;
            const float cc = s_cc[row];
            #pragma unroll
            for (int j = 0; j < 4; j++)
                out[(size_t)(r0 + row) * NCOL + c0 + tx + 16 * j] = acc[i][j] + cc;
        }

    } else if (bid < NB_CDIST + NB_SOFT) {
        // ---------------- soft-row family ----------------
        const int i = bid - NB_CDIST;
        float4* s_c  = (float4*)smem;        // 64 float4 = row i of centroids
        float* s_part = smem + 256;          // 4
        if (tid < 64)
            s_c[tid] = ((const float4*)(centroids + (size_t)i * 256))[tid];
        __syncthreads();

        float e = 0.f;
        if (tid < VOC) {
            float dij = 0.f, djj = 0.f, dii = 0.f;
            const float4* cj = (const float4*)(centroids + (size_t)tid * 256);
            #pragma unroll 4
            for (int k = 0; k < 64; k++) {
                float4 b = cj[k];
                float4 a = s_c[k];
                dij += a.x * b.x + a.y * b.y + a.z * b.z + a.w * b.w;
                djj += b.x * b.x + b.y * b.y + b.z * b.z + b.w * b.w;
                dii += a.x * a.x + a.y * a.y + a.z * a.z + a.w * a.w;
            }
            float sim = dij * rsqrtf(dii * djj);
            e = __expf(sim);
        }
        float s = e;
        #pragma unroll
        for (int off = 32; off; off >>= 1) s += __shfl_xor(s, off);
        const int wave = tid >> 6, lane = tid & 63;
        if (lane == 0) s_part[wave] = s;
        __syncthreads();
        float den = s_part[0] + s_part[1] + s_part[2] + s_part[3];
        if (tid < VOC) {
            float v = 0.15f * e / den;
            if (tid == i) v += 0.85f;
            soft[i * VOC + tid] = v;
        }

    } else {
        // ---------------- logP family: 1 wave = 1 bq, no LDS/barrier ------
        const int wave = tid >> 6, lane = tid & 63;
        const int bq   = (bid - (NB_CDIST + NB_SOFT)) * 4 + wave;
        const float* tl = pred_text_logits + (size_t)bq * NPTS * VOCP1;

        float acc0 = 0.f, acc1 = 0.f, acc96 = 0.f;
        #pragma unroll
        for (int g0 = 0; g0 < NPTS; g0 += 5) {
            float a[5], b[5];
            #pragma unroll
            for (int j = 0; j < 5; j++) {
                const float* row = tl + (size_t)(g0 + j) * VOCP1;
                a[j] = row[lane];
                b[j] = (lane < 33) ? row[64 + lane] : 0.f;
            }
            #pragma unroll
            for (int j = 0; j < 5; j++) {
                float ea = __expf(a[j]);
                float eb = (lane < 33) ? __expf(b[j]) : 0.f;
                float s = ea + eb;
                #pragma unroll
                for (int off = 32; off; off >>= 1) s += __shfl_xor(s, off);
                float inv = __builtin_amdgcn_rcpf(s);
                acc0  += ea * inv;
                acc1  += eb * inv;
                acc96 += __shfl(eb, 32) * inv;   // blank prob (v=96), uniform
            }
        }

        float denom = (25.0f - acc96) * (1.0f / NPTS) + (float)VOC * KL_EPS;
        float a0 = acc0 * (1.0f / NPTS);
        logP[(size_t)bq * VOC + lane] = __logf((a0 + KL_EPS) / denom);
        if (lane < 32) {
            float a1 = acc1 * (1.0f / NPTS);
            logP[(size_t)bq * VOC + 64 + lane] = __logf((a1 + KL_EPS) / denom);
        }
    }
}

// ==========================================================================
// K2: fused T-derivation + block-diagonal KL text cost (RMW on out).
// soft (37 KB) read straight from L2 (resident across all 400 blocks).
// ==========================================================================
__global__ __launch_bounds__(256) void K2(
        const int* __restrict__ tgt_texts,   // [512, 25]
        const float* __restrict__ soft,      // [96, 96]
        const float* __restrict__ logP,      // [NBQ, 96]
        float* __restrict__ out)             // [NBQ, 512]
{
    const int r0  = blockIdx.x * 8;       // 8 | 200: no batch crossing
    const int b   = r0 / NQ;
    const int tid = threadIdx.x;
    __shared__ int   s_chars[NGT * LSEQ];
    __shared__ float s_lp[8][VOC];
    __shared__ float s_Tt[VOC][NGT + 1];     // transposed, padded
    __shared__ float s_tl[NGT];
    __shared__ int   s_len[NGT];

    for (int i = tid; i < NGT * LSEQ; i += 256)
        s_chars[i] = tgt_texts[b * NGT * LSEQ + i];
    for (int i = tid; i < 8 * VOC; i += 256)
        s_lp[i / VOC][i % VOC] = logP[(size_t)r0 * VOC + i];
    __syncthreads();

    // --- T / TlogT / lens for this batch's 32 gts (soft read from L2) ---
    const int grp = tid >> 5, sub = tid & 31;
    for (int g = grp; g < NGT; g += 8) {
        int len = 0;
        float a0 = 0.f, a1 = 0.f, a2 = 0.f;
        for (int l = 0; l < LSEQ; l++) {
            int t = s_chars[g * LSEQ + l];
            if (t != VOC) {
                len++;
                const float* sr = soft + t * VOC;
                a0 += sr[sub]; a1 += sr[sub + 32]; a2 += sr[sub + 64];
            }
        }
        float inv = 1.f / (float)(len > 0 ? len : 1);
        a0 *= inv; a1 *= inv; a2 *= inv;
        float s = a0 + a1 + a2;
        #pragma unroll
        for (int off = 16; off; off >>= 1) s += __shfl_xor(s, off, 32);
        float denom = s + (float)VOC * KL_EPS;
        float t0 = (a0 + KL_EPS) / denom;
        float t1 = (a1 + KL_EPS) / denom;
        float t2 = (a2 + KL_EPS) / denom;
        s_Tt[sub][g]      = t0;
        s_Tt[sub + 32][g] = t1;
        s_Tt[sub + 64][g] = t2;
        float tl = t0 * __logf(t0) + t1 * __logf(t1) + t2 * __logf(t2);
        #pragma unroll
        for (int off = 16; off; off >>= 1) tl += __shfl_xor(tl, off, 32);
        if (sub == 0) { s_tl[g] = tl; s_len[g] = len; }
    }
    __syncthreads();

    // --- KL dot + diagonal RMW ---
    const int g = tid & 31, rs = tid >> 5;
    float d = 0.f;
    #pragma unroll 8
    for (int v = 0; v < VOC; v++) d += s_lp[rs][v] * s_Tt[v][g];
    float val = (s_len[g] == 0) ? 100.f : (s_tl[g] - d);
    size_t o = (size_t)(r0 + rs) * NCOL + b * NGT + g;
    out[o] += val;
}

extern "C" void kernel_launch(void* const* d_in, const int* in_sizes, int n_in,
                              void* d_out, int out_size, void* d_ws, size_t ws_size,
                              hipStream_t stream) {
    const float* pred_logits = (const float*)d_in[0];
    const float* pred_ctrl   = (const float*)d_in[1];
    const float* pred_text   = (const float*)d_in[2];
    const float* tgt_ctrl    = (const float*)d_in[3];
    const int*   tgt_texts   = (const int*)d_in[4];
    const float* centroids   = (const float*)d_in[5];
    float* out = (float*)d_out;

    float* ws   = (float*)d_ws;
    float* logP = ws;                        // 3200*96
    float* soft = logP + (size_t)NBQ * VOC;  // 96*96

    K1<<<NB_K1, 256, 0, stream>>>(pred_logits, pred_ctrl, pred_text,
                                  tgt_ctrl, centroids, logP, soft, out);
    K2<<<400, 256, 0, stream>>>(tgt_texts, soft, logP, out);
}

// Round 4
// 115.106 us; speedup vs baseline: 1.1025x; 1.1025x over previous
//
#include <hip/hip_runtime.h>

#define BS 16
#define NQ 200
#define NPTS 25
#define VOC 96
#define VOCP1 97
#define NGT 32
#define LSEQ 25
#define NCOL (BS*NGT)      // 512
#define NBQ (BS*NQ)        // 3200
#define KL_EPS 1e-6f
#define FOCAL_EPS 1e-8f

#define NB_CDIST 400                      // 50 row-tiles x 8 col-tiles
#define NB_SOFT VOC                       // 96 blocks: soft rows
#define NB_LOGP NBQ                       // 3200 blocks: 4 waves cooperate per bq
#define NB_K1 (NB_CDIST + NB_SOFT + NB_LOGP)  // 3696

// ==========================================================================
// K1: three independent block families, one launch, 13.06 KB LDS everywhere
// -> 8 blocks/CU (thread-limited) for all families.
//   [0, 400)    : 64x64 L1-cdist tiles. Only tgt tile staged in LDS;
//                 pred rows stream from global via L1 broadcast (4 addrs per
//                 wave-load). cost_class recomputed locally (x8 redundancy).
//   [400, 496)  : soft[96,96] rows (0.85*I + 0.15*softmax(cos-sim))
//   [496, 3696) : logP — 4 waves cooperate on one bq (wave w owns points
//                 w+4k); lane holds v=lane and v=64+lane; batched loads;
//                 6-step shfl row-sum; renorm denom via blank identity
//                 sum_{v<96} avg = (25 - sum_p p_blank)/25. One barrier
//                 (4x97 cross-wave combine). 12800 waves total = full TLP.
// ==========================================================================
__global__ __launch_bounds__(256) void K1(
        const float* __restrict__ pred_logits,       // [NBQ, 25]
        const float* __restrict__ pred_ctrl,         // [NBQ, 50]
        const float* __restrict__ pred_text_logits,  // [NBQ, 25, 97]
        const float* __restrict__ tgt_ctrl,          // [512, 50]
        const float* __restrict__ centroids,         // [96, 256]
        float* __restrict__ logP,                    // [NBQ, 96]
        float* __restrict__ soft,                    // [96, 96]
        float* __restrict__ out)                     // [NBQ, 512]
{
    __shared__ __align__(16) float smem[64 * 50 + 64];   // 13.06 KB
    const int tid = threadIdx.x;
    const int bid = blockIdx.x;

    if (bid < NB_CDIST) {
        // ---------------- cdist + cost_class family ----------------
        const int r0  = (bid >> 3) * 64;
        const int c0  = (bid & 7) * 64;
        float (*s_t)[50] = (float (*)[50])smem;              // 64*50
        float* s_cc = smem + 3200;                           // 64

        const float* tg = tgt_ctrl + (size_t)c0 * 50;
        for (int i = tid; i < 64 * 50; i += 256)
            ((float*)s_t)[i] = tg[i];
        // cost_class for this tile's 64 rows: 4 threads/row
        {
            const int row4 = tid >> 2, q4 = tid & 3;
            float cc = 0.f;
            for (int p = q4; p < NPTS; p += 4) {
                float x  = pred_logits[(size_t)(r0 + row4) * NPTS + p];
                float pr = 1.f / (1.f + __expf(-x));
                float pos = 0.25f * (1.f - pr) * (1.f - pr) * (-__logf(pr + FOCAL_EPS));
                float neg = 0.75f * pr * pr * (-__logf(1.f - pr + FOCAL_EPS));
                cc += pos - neg;
            }
            cc += __shfl_xor(cc, 1, 4);
            cc += __shfl_xor(cc, 2, 4);
            if (q4 == 0) s_cc[row4] = cc * (1.0f / NPTS);
        }
        __syncthreads();

        const int tx = tid & 15;       // col group (cols tx+16j)
        const int ty = tid >> 4;       // row group (rows ty*4+i)
        const float* prow[4];
        #pragma unroll
        for (int i = 0; i < 4; i++)
            prow[i] = pred_ctrl + (size_t)(r0 + ty * 4 + i) * 50;

        float acc[4][4];
        #pragma unroll
        for (int i = 0; i < 4; i++)
            #pragma unroll
            for (int j = 0; j < 4; j++) acc[i][j] = 0.f;

        #pragma unroll
        for (int k = 0; k < 50; k += 2) {
            float2 p[4], t[4];
            #pragma unroll
            for (int i = 0; i < 4; i++) p[i] = *(const float2*)(prow[i] + k);
            #pragma unroll
            for (int j = 0; j < 4; j++) t[j] = *(const float2*)&s_t[tx + 16 * j][k];
            #pragma unroll
            for (int i = 0; i < 4; i++)
                #pragma unroll
                for (int j = 0; j < 4; j++)
                    acc[i][j] += fabsf(p[i].x - t[j].x) + fabsf(p[i].y - t[j].y);
        }

        #pragma unroll
        for (int i = 0; i < 4; i++) {
            const int row = ty * 4 + i;
            const float cc = s_cc[row];
            #pragma unroll
            for (int j = 0; j < 4; j++)
                out[(size_t)(r0 + row) * NCOL + c0 + tx + 16 * j] = acc[i][j] + cc;
        }

    } else if (bid < NB_CDIST + NB_SOFT) {
        // ---------------- soft-row family ----------------
        const int i = bid - NB_CDIST;
        float4* s_c  = (float4*)smem;        // 64 float4 = row i of centroids
        float* s_part = smem + 256;          // 4
        if (tid < 64)
            s_c[tid] = ((const float4*)(centroids + (size_t)i * 256))[tid];
        __syncthreads();

        float e = 0.f;
        if (tid < VOC) {
            float dij = 0.f, djj = 0.f, dii = 0.f;
            const float4* cj = (const float4*)(centroids + (size_t)tid * 256);
            #pragma unroll 4
            for (int k = 0; k < 64; k++) {
                float4 b = cj[k];
                float4 a = s_c[k];
                dij += a.x * b.x + a.y * b.y + a.z * b.z + a.w * b.w;
                djj += b.x * b.x + b.y * b.y + b.z * b.z + b.w * b.w;
                dii += a.x * a.x + a.y * a.y + a.z * a.z + a.w * a.w;
            }
            float sim = dij * rsqrtf(dii * djj);
            e = __expf(sim);
        }
        float s = e;
        #pragma unroll
        for (int off = 32; off; off >>= 1) s += __shfl_xor(s, off);
        const int wave = tid >> 6, lane = tid & 63;
        if (lane == 0) s_part[wave] = s;
        __syncthreads();
        float den = s_part[0] + s_part[1] + s_part[2] + s_part[3];
        if (tid < VOC) {
            float v = 0.15f * e / den;
            if (tid == i) v += 0.85f;
            soft[i * VOC + tid] = v;
        }

    } else {
        // ---------------- logP family (4 waves cooperate per bq) ----------
        const int bq   = bid - (NB_CDIST + NB_SOFT);
        const int wave = tid >> 6, lane = tid & 63;
        float* s_acc = smem;          // [4][97]
        float* s_p96 = smem + 388;    // [4]

        const float* tl = pred_text_logits + (size_t)bq * NPTS * VOCP1;

        // batch-issue all loads: points p = wave + 4k (k<6), wave0 extra p=24
        float e0[7], e1[7];
        #pragma unroll
        for (int k = 0; k < 6; k++) {
            const float* row = tl + (size_t)(wave + 4 * k) * VOCP1;
            e0[k] = row[lane];
            e1[k] = (lane < 33) ? row[64 + lane] : 0.f;
        }
        if (wave == 0) {
            const float* row = tl + (size_t)24 * VOCP1;
            e0[6] = row[lane];
            e1[6] = (lane < 33) ? row[64 + lane] : 0.f;
        }

        float acc0 = 0.f, acc1 = 0.f, acc96 = 0.f;
        #pragma unroll
        for (int k = 0; k < 6; k++) {
            float a = __expf(e0[k]);
            float b = (lane < 33) ? __expf(e1[k]) : 0.f;
            float s = a + b;
            #pragma unroll
            for (int off = 32; off; off >>= 1) s += __shfl_xor(s, off);
            float inv = __builtin_amdgcn_rcpf(s);
            acc0  += a * inv;
            acc1  += b * inv;
            acc96 += __shfl(b, 32) * inv;      // blank prob (v=96), uniform
        }
        if (wave == 0) {
            float a = __expf(e0[6]);
            float b = (lane < 33) ? __expf(e1[6]) : 0.f;
            float s = a + b;
            #pragma unroll
            for (int off = 32; off; off >>= 1) s += __shfl_xor(s, off);
            float inv = __builtin_amdgcn_rcpf(s);
            acc0  += a * inv;
            acc1  += b * inv;
            acc96 += __shfl(b, 32) * inv;
        }

        s_acc[wave * VOCP1 + lane] = acc0;
        if (lane < 33) s_acc[wave * VOCP1 + 64 + lane] = acc1;
        if (lane == 0) s_p96[wave] = acc96;
        __syncthreads();

        if (tid < VOC) {
            float a = (s_acc[tid] + s_acc[VOCP1 + tid]
                     + s_acc[2 * VOCP1 + tid] + s_acc[3 * VOCP1 + tid]) * (1.0f / NPTS);
            float S96 = s_p96[0] + s_p96[1] + s_p96[2] + s_p96[3];
            float denom = (25.0f - S96) * (1.0f / NPTS) + (float)VOC * KL_EPS;
            logP[(size_t)bq * VOC + tid] = __logf((a + KL_EPS) / denom);
        }
    }
}

// ==========================================================================
// K2: fused T-derivation + block-diagonal KL text cost (RMW on out).
// soft (37 KB) read straight from L2 (resident across all 400 blocks).
// ==========================================================================
__global__ __launch_bounds__(256) void K2(
        const int* __restrict__ tgt_texts,   // [512, 25]
        const float* __restrict__ soft,      // [96, 96]
        const float* __restrict__ logP,      // [NBQ, 96]
        float* __restrict__ out)             // [NBQ, 512]
{
    const int r0  = blockIdx.x * 8;       // 8 | 200: no batch crossing
    const int b   = r0 / NQ;
    const int tid = threadIdx.x;
    __shared__ int   s_chars[NGT * LSEQ];
    __shared__ float s_lp[8][VOC];
    __shared__ float s_Tt[VOC][NGT + 1];     // transposed, padded
    __shared__ float s_tl[NGT];
    __shared__ int   s_len[NGT];

    for (int i = tid; i < NGT * LSEQ; i += 256)
        s_chars[i] = tgt_texts[b * NGT * LSEQ + i];
    for (int i = tid; i < 8 * VOC; i += 256)
        s_lp[i / VOC][i % VOC] = logP[(size_t)r0 * VOC + i];
    __syncthreads();

    // --- T / TlogT / lens for this batch's 32 gts (soft read from L2) ---
    const int grp = tid >> 5, sub = tid & 31;
    for (int g = grp; g < NGT; g += 8) {
        int len = 0;
        float a0 = 0.f, a1 = 0.f, a2 = 0.f;
        for (int l = 0; l < LSEQ; l++) {
            int t = s_chars[g * LSEQ + l];
            if (t != VOC) {
                len++;
                const float* sr = soft + t * VOC;
                a0 += sr[sub]; a1 += sr[sub + 32]; a2 += sr[sub + 64];
            }
        }
        float inv = 1.f / (float)(len > 0 ? len : 1);
        a0 *= inv; a1 *= inv; a2 *= inv;
        float s = a0 + a1 + a2;
        #pragma unroll
        for (int off = 16; off; off >>= 1) s += __shfl_xor(s, off, 32);
        float denom = s + (float)VOC * KL_EPS;
        float t0 = (a0 + KL_EPS) / denom;
        float t1 = (a1 + KL_EPS) / denom;
        float t2 = (a2 + KL_EPS) / denom;
        s_Tt[sub][g]      = t0;
        s_Tt[sub + 32][g] = t1;
        s_Tt[sub + 64][g] = t2;
        float tl = t0 * __logf(t0) + t1 * __logf(t1) + t2 * __logf(t2);
        #pragma unroll
        for (int off = 16; off; off >>= 1) tl += __shfl_xor(tl, off, 32);
        if (sub == 0) { s_tl[g] = tl; s_len[g] = len; }
    }
    __syncthreads();

    // --- KL dot + diagonal RMW ---
    const int g = tid & 31, rs = tid >> 5;
    float d = 0.f;
    #pragma unroll 8
    for (int v = 0; v < VOC; v++) d += s_lp[rs][v] * s_Tt[v][g];
    float val = (s_len[g] == 0) ? 100.f : (s_tl[g] - d);
    size_t o = (size_t)(r0 + rs) * NCOL + b * NGT + g;
    out[o] += val;
}

extern "C" void kernel_launch(void* const* d_in, const int* in_sizes, int n_in,
                              void* d_out, int out_size, void* d_ws, size_t ws_size,
                              hipStream_t stream) {
    const float* pred_logits = (const float*)d_in[0];
    const float* pred_ctrl   = (const float*)d_in[1];
    const float* pred_text   = (const float*)d_in[2];
    const float* tgt_ctrl    = (const float*)d_in[3];
    const int*   tgt_texts   = (const int*)d_in[4];
    const float* centroids   = (const float*)d_in[5];
    float* out = (float*)d_out;

    float* ws   = (float*)d_ws;
    float* logP = ws;                        // 3200*96
    float* soft = logP + (size_t)NBQ * VOC;  // 96*96

    K1<<<NB_K1, 256, 0, stream>>>(pred_logits, pred_ctrl, pred_text,
                                  tgt_ctrl, centroids, logP, soft, out);
    K2<<<400, 256, 0, stream>>>(tgt_texts, soft, logP, out);
}